// Round 11
// baseline (475.647 us; speedup 1.0000x reference)
//
#include <hip/hip_runtime.h>
#include <hip/hip_bf16.h>
#include <math.h>

#define N_CTX 4096
#define DM    2048

typedef __attribute__((ext_vector_type(8))) short short8;
typedef __attribute__((ext_vector_type(4))) float f32x4;
typedef unsigned short ushort_t;

__device__ __forceinline__ ushort_t f2bf(float x) {
    __hip_bfloat16 h = __float2bfloat16(x);
    return __builtin_bit_cast(ushort_t, h);
}
__device__ __forceinline__ float bf2f(ushort_t u) {
    return __bfloat162float(__builtin_bit_cast(__hip_bfloat16, u));
}

__device__ __forceinline__ void gload16(const void* g, void* l) {
    __builtin_amdgcn_global_load_lds((const __attribute__((address_space(1))) void*)g,
                                     (__attribute__((address_space(3))) void*)l,
                                     16, 0, 0);
}

// ---------------- cast kernels ----------------

__global__ __launch_bounds__(256) void split_cast_kernel(
    const float* __restrict__ in, ushort_t* __restrict__ hi, ushort_t* __restrict__ lo, int n4)
{
    int idx = blockIdx.x * 256 + threadIdx.x;
    if (idx >= n4) return;
    float4 v = reinterpret_cast<const float4*>(in)[idx];
    float vv[4] = {v.x, v.y, v.z, v.w};
    ushort_t h[4], l[4];
#pragma unroll
    for (int j = 0; j < 4; ++j) {
        h[j] = f2bf(vv[j]);
        l[j] = f2bf(vv[j] - bf2f(h[j]));
    }
    reinterpret_cast<ushort4*>(hi)[idx] = *reinterpret_cast<ushort4*>(h);
    reinterpret_cast<ushort4*>(lo)[idx] = *reinterpret_cast<ushort4*>(l);
}

template <bool SPLIT>
__global__ __launch_bounds__(256) void transpose_cast_kernel(
    const float* __restrict__ in, ushort_t* __restrict__ hi, ushort_t* __restrict__ lo,
    int R, int C)
{
    __shared__ float tile[32][33];
    int bc = blockIdx.x * 32;
    int br = blockIdx.y * 32;
    int tx = threadIdx.x, ty = threadIdx.y;   // (32, 8)
#pragma unroll
    for (int r = ty; r < 32; r += 8)
        tile[r][tx] = in[(size_t)(br + r) * C + bc + tx];
    __syncthreads();
#pragma unroll
    for (int c = ty; c < 32; c += 8) {
        float v = tile[tx][c];
        size_t o = (size_t)(bc + c) * R + br + tx;
        ushort_t h = f2bf(v);
        hi[o] = h;
        if (SPLIT) lo[o] = f2bf(v - bf2f(h));
    }
}

// ---------------- split GEMM: C = Ah@Bh^T + Ah@Bl^T + Al@Bh^T ----------------
// 256x128 tile, BK=32, 8 waves (4M x 2N, 64x64 each), dbuf dynamic LDS:
// per buf 48KB = AH(16K)+AL(16K)+BH(8K)+BL(8K); 2 bufs = 96KB -> 1 block/CU.
// Stage(t+1) issued BEFORE compute(t); one __syncthreads per K-step. Rationale:
// stage is L2-BW-bound (~48KB/step ~ 857cy/CU) and overlaps under ~900cy of
// ds_read+MFMA; the barrier drain is then cheap (r7 post-mortem).
// Bytes/FLOP: 7.6 KB/MFLOP vs 10.4 at 128^2 (-27%). Swizzle identical to r6/7
// (measured 0 bank conflicts): LDS chunk c holds global chunk c^((row>>1)&3).
// OM: 0 = f32 out, 2 = split bf16 out. CAUSAL: early-exit blocks above diag.

template <int OM, bool CAUSAL>
__global__ __launch_bounds__(512, 2) void gemm_split_kernel(
    const ushort_t* __restrict__ Ah, const ushort_t* __restrict__ Al,
    const ushort_t* __restrict__ Bh, const ushort_t* __restrict__ Bl,
    int K, int ldc,
    float* __restrict__ Cf, ushort_t* __restrict__ Ch, ushort_t* __restrict__ Cl)
{
    const int bx = blockIdx.x;   // N tile (128)
    const int by = blockIdx.y;   // M tile (256)
    if (CAUSAL && bx * 128 > by * 256 + 255) return;

    extern __shared__ char lds[];   // [2][48KB]

    const int t = threadIdx.x;      // 0..511
    const int l = t & 63;
    const int w = t >> 6;           // 0..7
    const int wr = w >> 1;          // 0..3 -> 64-row band of 256
    const int wc = w & 1;           // 0..1 -> 64-col band of 128
    const int lr = l & 15;
    const int lc = l >> 4;

    f32x4 acc[4][4];
#pragma unroll
    for (int m = 0; m < 4; ++m)
#pragma unroll
        for (int n = 0; n < 4; ++n) acc[m][n] = (f32x4){0.f, 0.f, 0.f, 0.f};

    const size_t arow0 = (size_t)by * 256;
    const size_t brow0 = (size_t)bx * 128;

    // A tile: 256 rows x 32 k (64B rows, 4 chunks) = 1024 chunks; 2 gloads/thr.
    auto stgA = [&](const ushort_t* src, char* dst, int kt) {
#pragma unroll
        for (int i2 = 0; i2 < 2; ++i2) {
            int f = i2 * 512 + t;
            int r = f >> 2, c = f & 3;
            gload16(src + (arow0 + r) * (size_t)K + kt + ((c ^ ((r >> 1) & 3)) << 3),
                    dst + f * 16);
        }
    };
    // B tile: 128 rows x 32 k = 512 chunks; 1 gload/thr.
    auto stgB = [&](const ushort_t* src, char* dst, int kt) {
        int r = t >> 2, c = t & 3;
        gload16(src + (brow0 + r) * (size_t)K + kt + ((c ^ ((r >> 1) & 3)) << 3),
                dst + t * 16);
    };
    auto stage = [&](int kt, int buf) {
        char* base = lds + buf * 49152;
        stgA(Ah, base, kt);
        stgA(Al, base + 16384, kt);
        stgB(Bh, base + 32768, kt);
        stgB(Bl, base + 40960, kt);
    };
    auto rdf = [&](short8* d, const char* base, int rbase) {
#pragma unroll
        for (int m = 0; m < 4; ++m) {
            int row = rbase + m * 16 + lr;
            d[m] = *(const short8*)(base + row * 64 + ((lc ^ ((row >> 1) & 3)) << 4));
        }
    };
    auto mm16 = [&](const short8* a, const short8* b) {
#pragma unroll
        for (int m = 0; m < 4; ++m)
#pragma unroll
            for (int n = 0; n < 4; ++n)
                acc[m][n] = __builtin_amdgcn_mfma_f32_16x16x32_bf16(
                    a[m], b[n], acc[m][n], 0, 0, 0);
    };

    stage(0, 0);
    __syncthreads();
    const int nt = K >> 5;
    for (int tt = 0; tt < nt; ++tt) {
        const int buf = tt & 1;
        const char* base = lds + buf * 49152;
        if (tt + 1 < nt) stage((tt + 1) << 5, buf ^ 1);
        short8 ah[4], bh[4], x[4];
        rdf(ah, base, wr * 64);
        rdf(bh, base + 32768, wc * 64);
        mm16(ah, bh);            // hi * hi
        rdf(x, base + 40960, wc * 64);
        mm16(ah, x);             // hi * lo
        rdf(x, base + 16384, wr * 64);
        mm16(x, bh);             // lo * hi
        __syncthreads();         // drains next-tile stage (issued ~900cy ago)
    }

    // epilogue: C/D layout col = lane&15, row = (lane>>4)*4 + reg
    const int r0 = by * 256 + wr * 64 + (lc << 2);
    const int c0 = bx * 128 + wc * 64 + lr;
#pragma unroll
    for (int m = 0; m < 4; ++m)
#pragma unroll
        for (int n = 0; n < 4; ++n)
#pragma unroll
            for (int j = 0; j < 4; ++j) {
                size_t o = (size_t)(r0 + m * 16 + j) * ldc + (c0 + n * 16);
                float v = acc[m][n][j];
                if (OM == 0) {
                    Cf[o] = v;
                } else {
                    ushort_t hh = f2bf(v);
                    Ch[o] = hh;
                    Cl[o] = f2bf(v - bf2f(hh));
                }
            }
}

// ---------------- plain GEMM (dbuf): C[M][N] = A @ B^T (unchanged r7) ----------------

template <int OM, bool CKLIM>
__global__ __launch_bounds__(256, 2) void gemm_bt_kernel(
    const ushort_t* __restrict__ A, const ushort_t* __restrict__ B,
    int K, int ldc,
    float* __restrict__ Cf, ushort_t* __restrict__ Ch)
{
    const int bx = blockIdx.x;
    const int by = blockIdx.y;

    __shared__ ushort_t lds[2][2][128 * 64];   // [buf][A,B] 64KB

    const int t = threadIdx.x;
    const int l = t & 63;
    const int w = t >> 6;
    const int wr = w >> 1;
    const int wc = w & 1;

    f32x4 acc[4][4];
#pragma unroll
    for (int m = 0; m < 4; ++m)
#pragma unroll
        for (int n = 0; n < 4; ++n) acc[m][n] = (f32x4){0.f, 0.f, 0.f, 0.f};

    const size_t arow0 = (size_t)by * 128;
    const size_t brow0 = (size_t)bx * 128;

    int kend = K;
    if (CKLIM) { int lim = (by + 1) * 128; if (lim < kend) kend = lim; }

    auto stage = [&](int kt, int buf) {
#pragma unroll
        for (int i2 = 0; i2 < 4; ++i2) {
            int f = i2 * 256 + t;
            int r = f >> 3, c = f & 7;
            gload16(A + (arow0 + r) * (size_t)K + kt + ((c ^ (r & 7)) << 3),
                    (char*)lds[buf][0] + f * 16);
            gload16(B + (brow0 + r) * (size_t)K + kt + ((c ^ (r & 7)) << 3),
                    (char*)lds[buf][1] + f * 16);
        }
    };

    stage(0, 0);
    __syncthreads();
    const int nt = kend >> 6;
    for (int tt = 0; tt < nt; ++tt) {
        const int buf = tt & 1;
        if (tt + 1 < nt) stage((tt + 1) << 6, buf ^ 1);
#pragma unroll
        for (int kk = 0; kk < 2; ++kk) {
            short8 af[4], bfr[4];
#pragma unroll
            for (int m = 0; m < 4; ++m) {
                int row = wr * 64 + m * 16 + (l & 15);
                int gby = kk * 64 + (l >> 4) * 16;
                af[m] = *(const short8*)((const char*)lds[buf][0] + row * 128 +
                                         (gby ^ ((row & 7) * 16)));
            }
#pragma unroll
            for (int n = 0; n < 4; ++n) {
                int row = wc * 64 + n * 16 + (l & 15);
                int gby = kk * 64 + (l >> 4) * 16;
                bfr[n] = *(const short8*)((const char*)lds[buf][1] + row * 128 +
                                          (gby ^ ((row & 7) * 16)));
            }
#pragma unroll
            for (int m = 0; m < 4; ++m)
#pragma unroll
                for (int n = 0; n < 4; ++n)
                    acc[m][n] = __builtin_amdgcn_mfma_f32_16x16x32_bf16(
                        af[m], bfr[n], acc[m][n], 0, 0, 0);
        }
        __syncthreads();
    }

    const int r0 = by * 128 + wr * 64 + ((l >> 4) << 2);
    const int c0 = bx * 128 + wc * 64 + (l & 15);
#pragma unroll
    for (int m = 0; m < 4; ++m)
#pragma unroll
        for (int n = 0; n < 4; ++n)
#pragma unroll
            for (int j = 0; j < 4; ++j) {
                size_t o = (size_t)(r0 + m * 16 + j) * ldc + (c0 + n * 16);
                if (OM == 0) Cf[o] = acc[m][n][j];
                else         Ch[o] = f2bf(acc[m][n][j]);
            }
}

// ---------------- causal row softmax ----------------

__device__ __forceinline__ float waveMax(float v) {
#pragma unroll
    for (int o = 32; o > 0; o >>= 1) v = fmaxf(v, __shfl_xor(v, o, 64));
    return v;
}
__device__ __forceinline__ float waveSum(float v) {
#pragma unroll
    for (int o = 32; o > 0; o >>= 1) v += __shfl_xor(v, o, 64);
    return v;
}

__global__ __launch_bounds__(256) void softmax_kernel(
    const float* __restrict__ S, ushort_t* __restrict__ A)
{
    const int i = blockIdx.x;
    __shared__ float row[N_CTX];
    __shared__ float red[8];
    const int t = threadIdx.x;
    const int len = i + 1;
    const float* Srow = S + (size_t)i * N_CTX;

    float m = -3.4e38f;
    for (int j = t; j < len; j += 256) {
        float v = Srow[j];
        row[j] = v;
        m = fmaxf(m, v);
    }
    m = waveMax(m);
    if ((t & 63) == 0) red[t >> 6] = m;
    __syncthreads();
    m = fmaxf(fmaxf(red[0], red[1]), fmaxf(red[2], red[3]));

    float s = 0.f;
    for (int j = t; j < len; j += 256) {
        float e = __expf(row[j] - m);
        row[j] = e;
        s += e;
    }
    s = waveSum(s);
    __syncthreads();
    if ((t & 63) == 0) red[t >> 6] = s;
    __syncthreads();
    float inv = 1.f / (red[0] + red[1] + red[2] + red[3]);

    ushort_t* Arow = A + (size_t)i * N_CTX;
    for (int j = t; j < N_CTX; j += 256)
        Arow[j] = (j < len) ? f2bf(row[j] * inv) : (ushort_t)0;
}

// ---------------- launcher ----------------

extern "C" void kernel_launch(void* const* d_in, const int* in_sizes, int n_in,
                              void* d_out, int out_size, void* d_ws, size_t ws_size,
                              hipStream_t stream)
{
    const float* E  = (const float*)d_in[0];
    const float* qk = (const float*)d_in[1];
    const float* ov = (const float*)d_in[2];
    float* out = (float*)d_out;

    char* ws = (char*)d_ws;
    size_t off = 0;
    auto take = [&](size_t bytes) -> char* {
        char* p = ws + off;
        off += (bytes + 255) & ~(size_t)255;
        return p;
    };

    ushort_t* Ehi   = (ushort_t*)take((size_t)N_CTX * DM * 2);
    ushort_t* Elo   = (ushort_t*)take((size_t)N_CTX * DM * 2);
    ushort_t* Et    = (ushort_t*)take((size_t)N_CTX * DM * 2);
    ushort_t* QKthi = (ushort_t*)take((size_t)DM * DM * 2);
    ushort_t* QKtlo = (ushort_t*)take((size_t)DM * DM * 2);
    ushort_t* OVt   = (ushort_t*)take((size_t)DM * DM * 2);
    ushort_t* Qhi   = (ushort_t*)take((size_t)N_CTX * DM * 2);
    ushort_t* Qlo   = (ushort_t*)take((size_t)N_CTX * DM * 2);
    float*    S     = (float*)take((size_t)N_CTX * N_CTX * 4);
    ushort_t* Attn  = (ushort_t*)take((size_t)N_CTX * N_CTX * 2);
    ushort_t* Hbf   = (ushort_t*)take((size_t)N_CTX * DM * 2);
    (void)ws_size; (void)in_sizes; (void)n_in; (void)out_size;

    constexpr int SMEM = 96 * 1024;
    hipFuncSetAttribute((const void*)&gemm_split_kernel<2, false>,
                        hipFuncAttributeMaxDynamicSharedMemorySize, SMEM);
    hipFuncSetAttribute((const void*)&gemm_split_kernel<0, true>,
                        hipFuncAttributeMaxDynamicSharedMemorySize, SMEM);

    // 1. casts
    split_cast_kernel<<<dim3((N_CTX * DM / 4) / 256), 256, 0, stream>>>(E, Ehi, Elo, N_CTX * DM / 4);
    transpose_cast_kernel<true ><<<dim3(DM / 32, DM / 32),    dim3(32, 8), 0, stream>>>(qk, QKthi, QKtlo, DM, DM);
    transpose_cast_kernel<false><<<dim3(DM / 32, DM / 32),    dim3(32, 8), 0, stream>>>(ov, OVt, nullptr, DM, DM);
    transpose_cast_kernel<false><<<dim3(DM / 32, N_CTX / 32), dim3(32, 8), 0, stream>>>(E, Et, nullptr, N_CTX, DM);

    // 2. Q = E @ qk  (fused 3-pass split, 256x128, split bf16 out). grid 16x16
    gemm_split_kernel<2, false><<<dim3(DM / 128, N_CTX / 256), 512, SMEM, stream>>>(
        Ehi, Elo, QKthi, QKtlo, DM, DM, nullptr, Qhi, Qlo);

    // 3. S = Q @ E^T  (fused 3-pass split, 256x128, causal early-exit, f32 out). grid 32x16
    gemm_split_kernel<0, true><<<dim3(N_CTX / 128, N_CTX / 256), 512, SMEM, stream>>>(
        Qhi, Qlo, Ehi, Elo, DM, N_CTX, S, nullptr, nullptr);

    // 4. attn = causal softmax(S), bf16
    softmax_kernel<<<N_CTX, 256, 0, stream>>>(S, Attn);

    // 5. H = attn @ E  (bf16 out, causal K-limit, dbuf)
    gemm_bt_kernel<1, true><<<dim3(DM / 128, N_CTX / 128), 256, 0, stream>>>(
        Attn, Et, N_CTX, DM, nullptr, Hbf);

    // 6. out = H @ ov  (f32 out, dbuf)
    gemm_bt_kernel<0, false><<<dim3(DM / 128, N_CTX / 128), 256, 0, stream>>>(
        Hbf, OVt, DM, DM, out, nullptr);
}